// Round 7
// baseline (637.443 us; speedup 1.0000x reference)
//
#include <hip/hip_runtime.h>
#include <hip/hip_cooperative_groups.h>
#include <math.h>

namespace cg = cooperative_groups;

#define N_NODES 100000
#define N_EDGES 1600000
#define EPS_    1e-5f
#define PAD     64          // ELL row capacity; P(Poisson(16) > 64) ~ 1e-20

#define NBLK     1024
#define NTHR     256
#define NTHREADS (NBLK * NTHR)        // 262144 threads
#define NWAVES   (NBLK * (NTHR / 64)) // 4096 waves

// ---- bf16 helpers (raw ushort storage, RNE on pack) -----------------------
__device__ __forceinline__ float bf2f(unsigned short u) {
    union { unsigned int i; float f; } v; v.i = (unsigned int)u << 16; return v.f;
}
__device__ __forceinline__ unsigned short f2bf(float f) {
    union { float f; unsigned int i; } v; v.f = f;
    unsigned int b = v.i + 0x7FFFu + ((v.i >> 16) & 1u);   // round-to-nearest-even
    return (unsigned short)(b >> 16);
}

// ---------------------------------------------------------------------------
// One cooperative kernel, 4 phases separated by grid.sync():
//   P0: zero cnt, stage Wg -> LDS
//   P1: per block: (a) ELL-build atomics for its edge chunk (memory-bound,
//       VALU idle), then (b) lin chunk h=relu(xW1+b1), hg=hWg (VALU-bound,
//       runs in the atomic drain's shadow). hg stored UNSCALED (no cnt dep).
//   P2: hb_g *= rsqrt(cnt+1)  (in place, dword grain)
//   P3: gather + LayerNorm epilogue -> out
// __launch_bounds__(256,4): <=128 VGPR guaranteed => 4 blocks/CU co-resident
// (LDS 16KB*4=64KB/CU OK) — safe for cooperative launch at 1024 blocks.
// ---------------------------------------------------------------------------
__global__ __launch_bounds__(NTHR, 4)
void fused_kernel(const int* __restrict__ src,
                  const int* __restrict__ dst,
                  const float* __restrict__ x,
                  const float* __restrict__ W1,
                  const float* __restrict__ b1,
                  const float* __restrict__ Wg,
                  const float* __restrict__ bg,
                  const float* __restrict__ gamma,
                  const float* __restrict__ beta,
                  int* __restrict__ cnt,
                  int* __restrict__ ell,
                  unsigned short* __restrict__ hb_h,
                  unsigned short* __restrict__ hb_g,
                  float* __restrict__ out)
{
    cg::grid_group grid = cg::this_grid();
    __shared__ float sWg[64 * 64];

    const int tl    = threadIdx.x;
    const int gtid  = blockIdx.x * NTHR + tl;
    const int lane  = tl & 63;
    const int gwave = blockIdx.x * (NTHR / 64) + (tl >> 6);

    // ---- P0: stage Wg to LDS; zero cnt -----------------------------------
    for (int i = tl; i < 64 * 64; i += NTHR) sWg[i] = Wg[i];
    if (gtid < N_NODES) cnt[gtid] = 0;           // N_NODES < NTHREADS
    grid.sync();

    // ---- P1a: ELL build (atomics issued early, drain overlaps P1b) -------
    for (int e = gtid; e < N_EDGES; e += NTHREADS) {
        const int d   = dst[e];
        const int s   = src[e];
        const int pos = atomicAdd(&cnt[d], 1);
        if (pos < PAD) ell[d * PAD + pos] = s;
    }

    // ---- P1b: lin (VALU work under the atomic shadow; hg unscaled) -------
    for (int n = gwave; n < N_NODES; n += NWAVES) {
        const float x0 = x[n * 3 + 0];
        const float x1 = x[n * 3 + 1];
        const float x2 = x[n * 3 + 2];
        float h = x0 * W1[lane] + x1 * W1[64 + lane] + x2 * W1[128 + lane] + b1[lane];
        h = fmaxf(h, 0.0f);

        float acc = 0.0f;
#pragma unroll 16
        for (int k = 0; k < 64; ++k) {
            const float hk = __shfl(h, k, 64);
            acc = fmaf(hk, sWg[k * 64 + lane], acc);
        }
        hb_h[n * 64 + lane] = f2bf(h);
        hb_g[n * 64 + lane] = f2bf(acc);
    }
    grid.sync();

    // ---- P2: scale hb_g by rsqrt(cnt+1), ushort2 (dword) grain -----------
    {
        unsigned int* __restrict__ g2 = (unsigned int*)hb_g;
        for (int t = gtid; t < N_NODES * 32; t += NTHREADS) {
            const int node = t >> 5;
            const float di = rsqrtf((float)(cnt[node] + 1));
            const unsigned int v = g2[t];
            const float lo = bf2f((unsigned short)(v & 0xFFFFu)) * di;
            const float hi = bf2f((unsigned short)(v >> 16)) * di;
            g2[t] = (unsigned int)f2bf(lo) | ((unsigned int)f2bf(hi) << 16);
        }
    }
    grid.sync();

    // ---- P3: gather + LayerNorm epilogue ---------------------------------
    for (int n = gwave; n < N_NODES; n += NWAVES) {
        const int c    = cnt[n];
        const float di = rsqrtf((float)(c + 1));
        const int deg  = (c < PAD) ? c : PAD;
        const int* __restrict__ row = ell + n * PAD;

        const float h = bf2f(hb_h[n * 64 + lane]);     // issue early
        float acc = bf2f(hb_g[n * 64 + lane]);         // self loop (scaled)

        int j = 0;
        for (; j + 8 <= deg; j += 8) {                 // 8 gathers in flight
            const int4 r0 = *(const int4*)(row + j);
            const int4 r1 = *(const int4*)(row + j + 4);
            const float a0 = bf2f(hb_g[r0.x * 64 + lane]);
            const float a1 = bf2f(hb_g[r0.y * 64 + lane]);
            const float a2 = bf2f(hb_g[r0.z * 64 + lane]);
            const float a3 = bf2f(hb_g[r0.w * 64 + lane]);
            const float a4 = bf2f(hb_g[r1.x * 64 + lane]);
            const float a5 = bf2f(hb_g[r1.y * 64 + lane]);
            const float a6 = bf2f(hb_g[r1.z * 64 + lane]);
            const float a7 = bf2f(hb_g[r1.w * 64 + lane]);
            acc += ((a0 + a1) + (a2 + a3)) + ((a4 + a5) + (a6 + a7));
        }
        if (j + 4 <= deg) {
            const int4 r0 = *(const int4*)(row + j);
            acc += (bf2f(hb_g[r0.x * 64 + lane]) + bf2f(hb_g[r0.y * 64 + lane]))
                 + (bf2f(hb_g[r0.z * 64 + lane]) + bf2f(hb_g[r0.w * 64 + lane]));
            j += 4;
        }
        for (; j < deg; ++j) acc += bf2f(hb_g[row[j] * 64 + lane]);

        float h2 = fmaxf(fmaf(di, acc, bg[lane]), 0.0f);

        float sum = h + h2;
#pragma unroll
        for (int o = 32; o > 0; o >>= 1) sum += __shfl_xor(sum, o, 64);
        const float mu = sum * (1.0f / 128.0f);

        const float d0 = h - mu;
        const float d1 = h2 - mu;
        float vs = d0 * d0 + d1 * d1;
#pragma unroll
        for (int o = 32; o > 0; o >>= 1) vs += __shfl_xor(vs, o, 64);
        const float r = rsqrtf(vs * (1.0f / 128.0f) + EPS_);

        out[n * 128 + lane]      = d0 * r * gamma[lane]      + beta[lane];
        out[n * 128 + 64 + lane] = d1 * r * gamma[64 + lane] + beta[64 + lane];
    }
}

// ---------------------------------------------------------------------------
extern "C" void kernel_launch(void* const* d_in, const int* in_sizes, int n_in,
                              void* d_out, int out_size, void* d_ws, size_t ws_size,
                              hipStream_t stream)
{
    const float* x     = (const float*)d_in[0];
    const int*   edge  = (const int*)  d_in[1];   // [2, E]: row0 = src, row1 = dst
    const float* W1    = (const float*)d_in[2];
    const float* b1    = (const float*)d_in[3];
    const float* Wg    = (const float*)d_in[4];
    const float* bg    = (const float*)d_in[5];
    const float* gamma = (const float*)d_in[6];
    const float* beta  = (const float*)d_in[7];
    float*       out   = (float*)d_out;

    // Workspace layout (~51.6 MB): hb_g | hb_h | ell | cnt  (16B-aligned)
    char*  ws  = (char*)d_ws;
    size_t p   = 0;
    unsigned short* hb_g = (unsigned short*)(ws + p); p += (size_t)N_NODES * 64 * sizeof(unsigned short);
    unsigned short* hb_h = (unsigned short*)(ws + p); p += (size_t)N_NODES * 64 * sizeof(unsigned short);
    int*            ell  = (int*)           (ws + p); p += (size_t)N_NODES * PAD * sizeof(int);
    int*            cnt  = (int*)           (ws + p);

    const int* src = edge;
    const int* dst = edge + N_EDGES;

    void* args[] = {
        (void*)&src, (void*)&dst, (void*)&x, (void*)&W1, (void*)&b1, (void*)&Wg,
        (void*)&bg, (void*)&gamma, (void*)&beta,
        (void*)&cnt, (void*)&ell, (void*)&hb_h, (void*)&hb_g, (void*)&out
    };
    hipLaunchCooperativeKernel((const void*)fused_kernel,
                               dim3(NBLK), dim3(NTHR), args, 0, stream);
}

// Round 8
// 271.962 us; speedup vs baseline: 2.3439x; 2.3439x over previous
//
#include <hip/hip_runtime.h>
#include <math.h>

#define N_NODES 100000
#define N_EDGES 1600000
#define EPS_    1e-5f
#define PAD     64          // ELL row capacity; P(Poisson(16) > 64) ~ 1e-20

#define NB_BUILD 6250       // ceil(E/256): one edge per thread, exact
#define NWAVES_L (NB_BUILD * 4)

// ---- bf16 helpers (raw ushort storage, RNE on pack) -----------------------
__device__ __forceinline__ float bf2f(unsigned short u) {
    union { unsigned int i; float f; } v; v.i = (unsigned int)u << 16; return v.f;
}
__device__ __forceinline__ unsigned short f2bf(float f) {
    union { float f; unsigned int i; } v; v.f = f;
    unsigned int b = v.i + 0x7FFFu + ((v.i >> 16) & 1u);   // round-to-nearest-even
    return (unsigned short)(b >> 16);
}

// ---------------------------------------------------------------------------
// Kernel 1: merged ELL build + lin. HOMOGENEOUS blocks (R5's heterogeneous
// split collapsed occupancy), NO __launch_bounds__ cap (R7's coop launch
// halved waves/CU), NO grid.sync. Phase A: each thread issues one edge's
// atomicAdd + scattered store (TCC transaction-bound, VALU idle). Phase B:
// the same block runs a lin chunk — pure VALU/LDS work that executes in the
// atomic drain's shadow. hg is stored UNSCALED (no dependence on final cnt).
// ---------------------------------------------------------------------------
__global__ void build_lin_kernel(const int* __restrict__ src,
                                 const int* __restrict__ dst,
                                 const float* __restrict__ x,
                                 const float* __restrict__ W1,
                                 const float* __restrict__ b1,
                                 const float* __restrict__ Wg,
                                 int* __restrict__ cnt,
                                 int* __restrict__ ell,
                                 unsigned short* __restrict__ hb_h,
                                 unsigned short* __restrict__ hb_g)
{
    __shared__ float sWg[64 * 64];
    const int tl   = threadIdx.x;
    const int gtid = blockIdx.x * 256 + tl;

    // ---- Phase A: edge atomics (issued first; store waits on return) -----
    int pos = -1, d = 0, s = 0;
    if (gtid < N_EDGES) {
        d   = dst[gtid];
        s   = src[gtid];
        pos = atomicAdd(&cnt[d], 1);
    }
    // Stage Wg -> LDS while the atomic is in flight (independent work).
    for (int i = tl; i < 64 * 64; i += 256) sWg[i] = Wg[i];
    if (pos >= 0 && pos < PAD) ell[d * PAD + pos] = s;
    __syncthreads();

    // ---- Phase B: lin chunk (VALU-bound, hides under atomic drain) -------
    const int lane  = tl & 63;
    const int gwave = blockIdx.x * 4 + (tl >> 6);
    for (int n = gwave; n < N_NODES; n += NWAVES_L) {
        const float x0 = x[n * 3 + 0];
        const float x1 = x[n * 3 + 1];
        const float x2 = x[n * 3 + 2];
        float h = x0 * W1[lane] + x1 * W1[64 + lane] + x2 * W1[128 + lane] + b1[lane];
        h = fmaxf(h, 0.0f);

        float acc = 0.0f;
#pragma unroll 16
        for (int k = 0; k < 64; ++k) {
            const float hk = __shfl(h, k, 64);
            acc = fmaf(hk, sWg[k * 64 + lane], acc);
        }
        hb_h[n * 64 + lane] = f2bf(h);
        hb_g[n * 64 + lane] = f2bf(acc);          // unscaled — cnt not final yet
    }
}

// ---------------------------------------------------------------------------
// Kernel 2: hb_g[n][c] *= rsqrt(cnt[n]+1)  (in place, dword grain, ~6 us)
// ---------------------------------------------------------------------------
__global__ void scale_kernel(const int* __restrict__ cnt,
                             unsigned int* __restrict__ g2)
{
    const int t = blockIdx.x * blockDim.x + threadIdx.x;
    if (t >= N_NODES * 32) return;
    const int node = t >> 5;
    const float di = rsqrtf((float)(cnt[node] + 1));
    const unsigned int v = g2[t];
    const float lo = bf2f((unsigned short)(v & 0xFFFFu)) * di;
    const float hi = bf2f((unsigned short)(v >> 16)) * di;
    g2[t] = (unsigned int)f2bf(lo) | ((unsigned int)f2bf(hi) << 16);
}

// ---------------------------------------------------------------------------
// Kernel 3: gather + epilogue. One wave per dst node, lane = channel.
//   acc = hgs[n] (self) + sum over ELL row hgs[src]   (dinv[src] pre-folded)
//   h2  = relu(dinv[n]*acc + bg);  out = LayerNorm128([h,h2])*gamma + beta
// ---------------------------------------------------------------------------
__global__ void gather_final_kernel(const unsigned short* __restrict__ hb_h,
                                    const unsigned short* __restrict__ hb_g,
                                    const int* __restrict__ cnt,
                                    const int* __restrict__ ell,
                                    const float* __restrict__ bg,
                                    const float* __restrict__ gamma,
                                    const float* __restrict__ beta,
                                    float* __restrict__ out)
{
    const int lane = threadIdx.x & 63;
    const int n    = blockIdx.x * (blockDim.x >> 6) + (threadIdx.x >> 6);
    if (n >= N_NODES) return;

    const int c    = cnt[n];
    const float di = rsqrtf((float)(c + 1));
    const int deg  = (c < PAD) ? c : PAD;
    const int* __restrict__ row = ell + n * PAD;

    const float h = bf2f(hb_h[n * 64 + lane]);       // issue early
    float acc = bf2f(hb_g[n * 64 + lane]);           // self loop (scaled)

    int j = 0;
    for (; j + 8 <= deg; j += 8) {                   // 8 gathers in flight
        const int4 r0 = *(const int4*)(row + j);
        const int4 r1 = *(const int4*)(row + j + 4);
        const float a0 = bf2f(hb_g[r0.x * 64 + lane]);
        const float a1 = bf2f(hb_g[r0.y * 64 + lane]);
        const float a2 = bf2f(hb_g[r0.z * 64 + lane]);
        const float a3 = bf2f(hb_g[r0.w * 64 + lane]);
        const float a4 = bf2f(hb_g[r1.x * 64 + lane]);
        const float a5 = bf2f(hb_g[r1.y * 64 + lane]);
        const float a6 = bf2f(hb_g[r1.z * 64 + lane]);
        const float a7 = bf2f(hb_g[r1.w * 64 + lane]);
        acc += ((a0 + a1) + (a2 + a3)) + ((a4 + a5) + (a6 + a7));
    }
    if (j + 4 <= deg) {
        const int4 r0 = *(const int4*)(row + j);
        acc += (bf2f(hb_g[r0.x * 64 + lane]) + bf2f(hb_g[r0.y * 64 + lane]))
             + (bf2f(hb_g[r0.z * 64 + lane]) + bf2f(hb_g[r0.w * 64 + lane]));
        j += 4;
    }
    for (; j < deg; ++j) acc += bf2f(hb_g[row[j] * 64 + lane]);

    float h2 = fmaxf(fmaf(di, acc, bg[lane]), 0.0f);

    float sum = h + h2;
#pragma unroll
    for (int o = 32; o > 0; o >>= 1) sum += __shfl_xor(sum, o, 64);
    const float mu = sum * (1.0f / 128.0f);

    const float d0 = h - mu;
    const float d1 = h2 - mu;
    float vs = d0 * d0 + d1 * d1;
#pragma unroll
    for (int o = 32; o > 0; o >>= 1) vs += __shfl_xor(vs, o, 64);
    const float r = rsqrtf(vs * (1.0f / 128.0f) + EPS_);

    out[n * 128 + lane]      = d0 * r * gamma[lane]      + beta[lane];
    out[n * 128 + 64 + lane] = d1 * r * gamma[64 + lane] + beta[64 + lane];
}

// ---------------------------------------------------------------------------
extern "C" void kernel_launch(void* const* d_in, const int* in_sizes, int n_in,
                              void* d_out, int out_size, void* d_ws, size_t ws_size,
                              hipStream_t stream)
{
    const float* x     = (const float*)d_in[0];
    const int*   edge  = (const int*)  d_in[1];   // [2, E]: row0 = src, row1 = dst
    const float* W1    = (const float*)d_in[2];
    const float* b1    = (const float*)d_in[3];
    const float* Wg    = (const float*)d_in[4];
    const float* bg    = (const float*)d_in[5];
    const float* gamma = (const float*)d_in[6];
    const float* beta  = (const float*)d_in[7];
    float*       out   = (float*)d_out;

    // Workspace layout (~51.6 MB): hb_g | hb_h | ell | cnt  (16B-aligned)
    char*  ws  = (char*)d_ws;
    size_t p   = 0;
    unsigned short* hb_g = (unsigned short*)(ws + p); p += (size_t)N_NODES * 64 * sizeof(unsigned short);
    unsigned short* hb_h = (unsigned short*)(ws + p); p += (size_t)N_NODES * 64 * sizeof(unsigned short);
    int*            ell  = (int*)           (ws + p); p += (size_t)N_NODES * PAD * sizeof(int);
    int*            cnt  = (int*)           (ws + p);

    const int* src = edge;
    const int* dst = edge + N_EDGES;

    hipMemsetAsync(cnt, 0, (size_t)N_NODES * sizeof(int), stream);

    build_lin_kernel<<<NB_BUILD, 256, 0, stream>>>(src, dst, x, W1, b1, Wg,
                                                   cnt, ell, hb_h, hb_g);
    scale_kernel<<<(N_NODES * 32 + 255) / 256, 256, 0, stream>>>(cnt, (unsigned int*)hb_g);
    gather_final_kernel<<<(N_NODES + 3) / 4, 256, 0, stream>>>(hb_h, hb_g, cnt, ell,
                                                               bg, gamma, beta, out);
}